// Round 14
// baseline (2805.830 us; speedup 1.0000x reference)
//
#include <hip/hip_runtime.h>

#define HID 128
#define BR  128        // GEMM rows per block
#define FILL_CHUNK 2048

typedef _Float16 f16;
typedef f16 f16x2 __attribute__((ext_vector_type(2)));
typedef f16 f16x4 __attribute__((ext_vector_type(4)));
typedef f16 f16x8 __attribute__((ext_vector_type(8)));
typedef float f32x4 __attribute__((ext_vector_type(4)));

static __device__ __forceinline__ float2 h2f(unsigned int u) {
    f16x2 v;
    __builtin_memcpy(&v, &u, 4);
    return make_float2((float)v[0], (float)v[1]);
}

// physical XCD id (HW_REG_XCC_ID = 20, gfx940+); masked to 0..7
static __device__ __forceinline__ int xcc_id() {
    return __builtin_amdgcn_s_getreg((31 << 11) | 20) & 7;
}

// ================= CSR build, pass 1: bucket + count =================
// One streamed read of the edge list. (row,col) pairs appended to 8 dest-range
// buckets via wave-aggregated cursor reservations (sequential writes -> full
// lines). In-degree atomics privatized by PHYSICAL XCD -> slice is L2-local.

__global__ void k_bucket(const int* __restrict__ row, const int* __restrict__ col,
                         int* __restrict__ cnt8, int* __restrict__ bcur,
                         unsigned long long* __restrict__ bucket_buf, int E, int N, int CAP) {
    const int per = (N + 7) >> 3;
    int* cnt = cnt8 + (size_t)xcc_id() * N;
    const int lane = threadIdx.x & 63;
    const int eend = min(E, (blockIdx.x + 1) * FILL_CHUNK);

    for (int e = blockIdx.x * FILL_CHUNK + threadIdx.x; ; e += 256) {
        bool valid = e < eend;
        if (!__ballot(valid)) break;     // wave-uniform exit
        int c = 0, r = 0, b = -1;
        if (valid) {
            c = __builtin_nontemporal_load(col + e);
            r = __builtin_nontemporal_load(row + e);
            atomicAdd(&cnt[c], 1);
            b = c / per;
        }
#pragma unroll
        for (int bb = 0; bb < 8; ++bb) {
            unsigned long long m = __ballot(b == bb);
            if (m == 0ULL) continue;
            if (b == bb) {
                int leader = __ffsll((long long)m) - 1;
                int rank = __popcll(m & ((1ULL << lane) - 1));
                int base = 0;
                if (lane == leader) base = atomicAdd(&bcur[bb], __popcll(m));
                base = __shfl(base, leader);
                bucket_buf[(size_t)bb * CAP + base + rank] =
                    ((unsigned long long)(unsigned)c << 32) | (unsigned)r;
            }
        }
    }
}

// sums the 8 count slices, emits dinv, then block-exclusive scan
__global__ void k_scan_block(const int* __restrict__ cnt8, int* __restrict__ excl,
                             int* __restrict__ bsum, float* __restrict__ dinv, int N) {
    __shared__ int s[256];
    int i = blockIdx.x * 256 + threadIdx.x;
    int v = 0;
    if (i < N) {
#pragma unroll
        for (int x = 0; x < 8; ++x) v += cnt8[(size_t)x * N + i];
        dinv[i] = 1.0f / sqrtf((float)(v + 1));   // +1 = self-loop
    }
    s[threadIdx.x] = v;
    __syncthreads();
    for (int off = 1; off < 256; off <<= 1) {
        int t = (threadIdx.x >= off) ? s[threadIdx.x - off] : 0;
        __syncthreads();
        s[threadIdx.x] += t;
        __syncthreads();
    }
    if (i < N) excl[i] = s[threadIdx.x] - v;
    if (threadIdx.x == 255) bsum[blockIdx.x] = s[255];
}

__global__ __launch_bounds__(1024) void k_scan_bsum(int* __restrict__ bsum, int nb) {
    __shared__ int s[1024];
    int i = threadIdx.x;
    int v = (i < nb) ? bsum[i] : 0;
    s[i] = v;
    __syncthreads();
    for (int off = 1; off < 1024; off <<= 1) {
        int t = (i >= off) ? s[i - off] : 0;
        __syncthreads();
        s[i] += t;
        __syncthreads();
    }
    if (i < nb) bsum[i] = s[i] - v;
}

__global__ void k_scan_add(int* __restrict__ row_ptr, const int* __restrict__ bsum,
                           int* __restrict__ fill, int N, int E) {
    int i = blockIdx.x * 256 + threadIdx.x;
    if (i < N) {
        int v = row_ptr[i] + bsum[blockIdx.x];
        row_ptr[i] = v;
        fill[i] = v;
    }
    if (i == 0) row_ptr[N] = E;
}

// ================= CSR build, pass 2: XCD-affine scatter =================
// 2048 persistent blocks. Each block processes chunks of the bucket matching its
// PHYSICAL XCD (atomic tickets), then work-steals other buckets (correct even if
// XCC_ID were wrong). All writes to a csr_src line thus come from one XCD ->
// each line written back once.

__global__ __launch_bounds__(256) void k_fill2(const unsigned long long* __restrict__ bucket_buf,
                                               const int* __restrict__ bcur,
                                               int* __restrict__ tick,
                                               int* __restrict__ fill,
                                               int* __restrict__ csr_src, int CAP) {
    const int x = xcc_id();
    for (int k = 0; k < 8; ++k) {
        const int bb = (x + k) & 7;
        const int sz = min(bcur[bb], CAP);
        while (true) {
            __shared__ int ts;
            if (threadIdx.x == 0) ts = atomicAdd(&tick[bb], 1);
            __syncthreads();
            const int t = ts;
            __syncthreads();
            const int beg = t * FILL_CHUNK;
            if (beg >= sz) break;
            const int end2 = min(sz, beg + FILL_CHUNK);
            for (int i = beg + threadIdx.x; i < end2; i += 256) {
                unsigned long long u =
                    __builtin_nontemporal_load(&bucket_buf[(size_t)bb * CAP + i]);
                int c = (int)(u >> 32);
                int r = (int)(u & 0xffffffffu);
                int p = atomicAdd(&fill[c], 1);
                csr_src[p] = r;
            }
            __syncthreads();
        }
    }
}

// ================= W prep (all 3 layers, one launch) =================
// element (k,n) -> (k>>3)*1024 + n*8 + (k&7); hi [0,16384), lo [16384,32768)

__global__ void k_wprep3(const float* __restrict__ W0, const float* __restrict__ W1,
                         const float* __restrict__ W2, f16* __restrict__ out) {
    const int b = blockIdx.x;              // 48 blocks
    const int which = b >> 4;
    const float* W = which == 0 ? W0 : (which == 1 ? W1 : W2);
    f16* o = out + which * 32768;
    int i = (b & 15) * 256 + threadIdx.x;  // 4096 float4s
    int k = i >> 5, n0 = (i & 31) * 4;
    float4 v = reinterpret_cast<const float4*>(W)[i];
    float vv[4] = {v.x, v.y, v.z, v.w};
#pragma unroll
    for (int e = 0; e < 4; ++e) {
        int n = n0 + e;
        int idx = (k >> 3) * 1024 + n * 8 + (k & 7);
        f16 h = (f16)vv[e];
        o[idx] = h;
        o[16384 + idx] = (f16)(vv[e] - (float)h);
    }
}

// ================= GEMM: H16 = f16( dinv .* (X @ W) ) =================
// Swapped-operand MFMA: D = mfma(A=W^T-frag, B=X-frag); f16x4 epilogue stores.
// MODE 0: f32 input, 3 limbs, 64 KB LDS, swizzle at stage.
// MODE 1: f16 input PRE-SWIZZLED + PRE-RELU'd by agg -> linear 32 KB copy.

template<int MODE>
__global__ __launch_bounds__(512, 4) void k_gemm(const void* __restrict__ Xv,
                                                 const f16* __restrict__ Wt,
                                                 const float* __restrict__ dinv,
                                                 f16* __restrict__ H, int N) {
    __shared__ f16 Xs[MODE == 0 ? 2 * 16384 : 16384];
    const int t = threadIdx.x;
    const int row0 = blockIdx.x * BR;

    const int w  = t >> 6;
    const int l  = t & 63;
    const int lg = l >> 4;
    const int li = l & 15;
    const int ng = w & 3;           // 0..3 -> n-blocks ng*2, ng*2+1
    const int mg = w >> 2;          // 0..1 -> m-blocks mg*4 .. +3

    // W fragments (A operand), issued before X staging (latency hidden)
    f16x8 Wh[2][4], Wl[2][4];
#pragma unroll
    for (int nb = 0; nb < 2; ++nb) {
        const int ncol = (ng * 2 + nb) * 16 + li;
#pragma unroll
        for (int ks = 0; ks < 4; ++ks) {
            const int idx = (ks * 4 + lg) * 1024 + ncol * 8;
            Wh[nb][ks] = *reinterpret_cast<const f16x8*>(&Wt[idx]);
            Wl[nb][ks] = *reinterpret_cast<const f16x8*>(&Wt[16384 + idx]);
        }
    }

    if constexpr (MODE == 0) {
        const float* X = (const float*)Xv;
        for (int i = t; i < 4096; i += 512) {
            int r = i >> 5, q = i & 31;
            int gr = row0 + r;
            float4 v = make_float4(0.f, 0.f, 0.f, 0.f);
            if (gr < N) v = reinterpret_cast<const float4*>(X + (size_t)gr * HID)[q];
            f16 h0 = (f16)v.x, h1 = (f16)v.y, h2 = (f16)v.z, h3 = (f16)v.w;
            f16 l0 = (f16)(v.x - (float)h0), l1 = (f16)(v.y - (float)h1);
            f16 l2 = (f16)(v.z - (float)h2), l3 = (f16)(v.w - (float)h3);
            int base = r * 128 + (((q >> 1) ^ (r & 7)) * 8) + (q & 1) * 4;
            *reinterpret_cast<f16x4*>(&Xs[base])         = (f16x4){h0, h1, h2, h3};
            *reinterpret_cast<f16x4*>(&Xs[16384 + base]) = (f16x4){l0, l1, l2, l3};
        }
    } else {
        const f16* src = (const f16*)Xv + (size_t)row0 * HID;
        for (int i = t; i < 2048; i += 512)
            *reinterpret_cast<f16x8*>(&Xs[i * 8]) = *reinterpret_cast<const f16x8*>(src + (size_t)i * 8);
    }
    __syncthreads();

    f32x4 acc[2][4];
#pragma unroll
    for (int nb = 0; nb < 2; ++nb)
#pragma unroll
        for (int mb = 0; mb < 4; ++mb) acc[nb][mb] = (f32x4){0.f, 0.f, 0.f, 0.f};

#pragma unroll
    for (int mb = 0; mb < 4; ++mb) {
        const int arow = mg * 64 + mb * 16 + li;
#pragma unroll
        for (int ks = 0; ks < 4; ++ks) {
            const int idx = arow * 128 + (((ks * 4 + lg) ^ (arow & 7)) * 8);
            f16x8 Xh = *reinterpret_cast<const f16x8*>(&Xs[idx]);
#pragma unroll
            for (int nb = 0; nb < 2; ++nb) {
                acc[nb][mb] = __builtin_amdgcn_mfma_f32_16x16x32_f16(Wh[nb][ks], Xh, acc[nb][mb], 0, 0, 0);
                acc[nb][mb] = __builtin_amdgcn_mfma_f32_16x16x32_f16(Wl[nb][ks], Xh, acc[nb][mb], 0, 0, 0);
            }
            if constexpr (MODE == 0) {
                f16x8 Xl = *reinterpret_cast<const f16x8*>(&Xs[16384 + idx]);
#pragma unroll
                for (int nb = 0; nb < 2; ++nb)
                    acc[nb][mb] = __builtin_amdgcn_mfma_f32_16x16x32_f16(Wh[nb][ks], Xl, acc[nb][mb], 0, 0, 0);
            }
        }
    }

#pragma unroll
    for (int mb = 0; mb < 4; ++mb) {
        const int m = row0 + mg * 64 + mb * 16 + li;
        if (m < N) {
            const float d = dinv[m];
#pragma unroll
            for (int nb = 0; nb < 2; ++nb) {
                f16x4 o = {(f16)(acc[nb][mb][0] * d), (f16)(acc[nb][mb][1] * d),
                           (f16)(acc[nb][mb][2] * d), (f16)(acc[nb][mb][3] * d)};
                *reinterpret_cast<f16x4*>(&H[(size_t)m * HID + (ng * 2 + nb) * 16 + lg * 4]) = o;
            }
        }
    }
}

// ================= aggregation (row-gather, 2 nodes/wave, unroll 8) =================
// 32 lanes per node; lane owns uint2 (4 cols). F16OUT: store relu'd, LDS-swizzled
// f16 activation (consumed by gemm<1> as a linear copy); else plain f32 output.

template<bool F16OUT>
__global__ __launch_bounds__(256) void k_agg_csr(const f16* __restrict__ h,
                                                 const int* __restrict__ csr_src,
                                                 const int* __restrict__ row_ptr,
                                                 const float* __restrict__ dinv,
                                                 const float* __restrict__ bias,
                                                 void* __restrict__ outv, int N) {
    const int node = blockIdx.x * 8 + (threadIdx.x >> 5);
    if (node >= N) return;
    const int l = threadIdx.x & 31;
    const uint2* h2 = reinterpret_cast<const uint2*>(h);   // row = 32 uint2

    uint2 us = h2[(size_t)node * 32 + l];
    float2 a0 = h2f(us.x), a1 = h2f(us.y);
    float acc0 = a0.x, acc1 = a0.y, acc2 = a1.x, acc3 = a1.y;

    int j = row_ptr[node];
    const int end = row_ptr[node + 1];

    for (; j + 8 <= end; j += 8) {
        int s0 = csr_src[j];
        int s1 = csr_src[j + 1];
        int s2 = csr_src[j + 2];
        int s3 = csr_src[j + 3];
        int s4 = csr_src[j + 4];
        int s5 = csr_src[j + 5];
        int s6 = csr_src[j + 6];
        int s7 = csr_src[j + 7];
        uint2 u0 = h2[(size_t)s0 * 32 + l];
        uint2 u1 = h2[(size_t)s1 * 32 + l];
        uint2 u2 = h2[(size_t)s2 * 32 + l];
        uint2 u3 = h2[(size_t)s3 * 32 + l];
        uint2 u4 = h2[(size_t)s4 * 32 + l];
        uint2 u5 = h2[(size_t)s5 * 32 + l];
        uint2 u6 = h2[(size_t)s6 * 32 + l];
        uint2 u7 = h2[(size_t)s7 * 32 + l];
        float2 v0 = h2f(u0.x), w0 = h2f(u0.y), v1 = h2f(u1.x), w1 = h2f(u1.y);
        float2 v2 = h2f(u2.x), w2 = h2f(u2.y), v3 = h2f(u3.x), w3 = h2f(u3.y);
        float2 v4 = h2f(u4.x), w4 = h2f(u4.y), v5 = h2f(u5.x), w5 = h2f(u5.y);
        float2 v6 = h2f(u6.x), w6 = h2f(u6.y), v7 = h2f(u7.x), w7 = h2f(u7.y);
        acc0 += ((v0.x + v1.x) + (v2.x + v3.x)) + ((v4.x + v5.x) + (v6.x + v7.x));
        acc1 += ((v0.y + v1.y) + (v2.y + v3.y)) + ((v4.y + v5.y) + (v6.y + v7.y));
        acc2 += ((w0.x + w1.x) + (w2.x + w3.x)) + ((w4.x + w5.x) + (w6.x + w7.x));
        acc3 += ((w0.y + w1.y) + (w2.y + w3.y)) + ((w4.y + w5.y) + (w6.y + w7.y));
    }
    for (; j < end; ++j) {
        uint2 u = h2[(size_t)csr_src[j] * 32 + l];
        float2 v = h2f(u.x), w = h2f(u.y);
        acc0 += v.x; acc1 += v.y; acc2 += w.x; acc3 += w.y;
    }

    const float di = dinv[node];
    const float4 bv = reinterpret_cast<const float4*>(bias)[l];
    float o0 = fmaf(di, acc0, bv.x);
    float o1 = fmaf(di, acc1, bv.y);
    float o2 = fmaf(di, acc2, bv.z);
    float o3 = fmaf(di, acc3, bv.w);

    if constexpr (F16OUT) {
        o0 = fmaxf(o0, 0.f); o1 = fmaxf(o1, 0.f);
        o2 = fmaxf(o2, 0.f); o3 = fmaxf(o3, 0.f);
        const int swz = (((l >> 1) ^ (node & 7)) << 1) | (l & 1);
        f16x4 o = {(f16)o0, (f16)o1, (f16)o2, (f16)o3};
        *reinterpret_cast<f16x4*>((f16*)outv + (size_t)node * HID + swz * 4) = o;
    } else {
        *reinterpret_cast<float4*>((float*)outv + (size_t)node * HID + l * 4) =
            make_float4(o0, o1, o2, o3);
    }
}

// ================= launch =================

extern "C" void kernel_launch(void* const* d_in, const int* in_sizes, int n_in,
                              void* d_out, int out_size, void* d_ws, size_t ws_size,
                              hipStream_t stream) {
    const float* x  = (const float*)d_in[0];
    const int*   ei = (const int*)  d_in[1];
    const float* W0 = (const float*)d_in[2];
    const float* b0 = (const float*)d_in[3];
    const float* W1 = (const float*)d_in[4];
    const float* b1 = (const float*)d_in[5];
    const float* W2 = (const float*)d_in[6];
    const float* b2 = (const float*)d_in[7];

    const int N = in_sizes[0] / HID;
    const int E = in_sizes[1] / 2;
    const int* row = ei;        // sources
    const int* col = ei + E;    // destinations

    const int nb_n = (N + 255) / 256;
    const int CAP  = E / 8 + 8192;

    // workspace layout
    f16*   h16     = (f16*)d_ws;                      // [N,128] f16; pass-1 bucket_buf aliases this
    unsigned long long* bucket = (unsigned long long*)d_ws;  // [8][CAP] (used only before gemm0)
    float* dinv    = (float*)(h16 + (size_t)N * HID); // [N]
    int*   cnt8    = (int*)(dinv + N);                // [8][N]
    int*   bcur    = cnt8 + (size_t)8 * N;            // [8]
    int*   tick    = bcur + 8;                        // [8]
    int*   row_ptr = tick + 8;                        // [N+1]
    int*   fill    = row_ptr + (N + 1);               // [N]
    int*   bsum    = fill + N;                        // [nb_n]
    int*   csr_src = bsum + nb_n;                     // [E]
    f16*   wt      = (f16*)(csr_src + E);             // [3*32768]
    f16*   wt0     = wt;
    f16*   wt1     = wt + 32768;
    f16*   wt2     = wt + 65536;
    f16*   act     = (f16*)d_out;                     // layers 0,1 activation (f16, swizzled, relu'd)
    float* out     = (float*)d_out;                   // final f32 output

    const int nb_gemm  = (N + BR - 1) / BR;
    const int nb_agg   = (N + 7) / 8;                 // 2 nodes per wave
    const int nb_chunk = (E + FILL_CHUNK - 1) / FILL_CHUNK;

    // ---- CSR build + W prep ----
    (void)hipMemsetAsync(cnt8, 0, ((size_t)8 * N + 16) * sizeof(int), stream);
    k_wprep3<<<48, 256, 0, stream>>>(W0, W1, W2, wt);
    k_bucket<<<nb_chunk, 256, 0, stream>>>(row, col, cnt8, bcur, bucket, E, N, CAP);
    k_scan_block<<<nb_n, 256, 0, stream>>>(cnt8, row_ptr, bsum, dinv, N);
    k_scan_bsum <<<1, 1024, 0, stream>>>(bsum, nb_n);
    k_scan_add  <<<nb_n, 256, 0, stream>>>(row_ptr, bsum, fill, N, E);
    k_fill2     <<<2048, 256, 0, stream>>>(bucket, bcur, tick, fill, csr_src, CAP);

    // ---- layer 0: x (f32) -> h16 -> act (f16, swizzled+relu) ----
    k_gemm<0>      <<<nb_gemm, 512, 0, stream>>>(x, wt0, dinv, h16, N);
    k_agg_csr<true><<<nb_agg, 256, 0, stream>>>(h16, csr_src, row_ptr, dinv, b0, act, N);
    // ---- layer 1: act -> h16 -> act ----
    k_gemm<1>      <<<nb_gemm, 512, 0, stream>>>(act, wt1, dinv, h16, N);
    k_agg_csr<true><<<nb_agg, 256, 0, stream>>>(h16, csr_src, row_ptr, dinv, b1, act, N);
    // ---- layer 2: act -> h16 -> out (f32) ----
    k_gemm<1>      <<<nb_gemm, 512, 0, stream>>>(act, wt2, dinv, h16, N);
    k_agg_csr<false><<<nb_agg, 256, 0, stream>>>(h16, csr_src, row_ptr, dinv, b2, out, N);
}

// Round 15
// 424.140 us; speedup vs baseline: 6.6153x; 6.6153x over previous
//
#include <hip/hip_runtime.h>

#define HID 128
#define BR  128        // GEMM rows per block
#define FILL_CHUNK 2048

typedef _Float16 f16;
typedef f16 f16x2 __attribute__((ext_vector_type(2)));
typedef f16 f16x4 __attribute__((ext_vector_type(4)));
typedef f16 f16x8 __attribute__((ext_vector_type(8)));
typedef float f32x4 __attribute__((ext_vector_type(4)));

static __device__ __forceinline__ float2 h2f(unsigned int u) {
    f16x2 v;
    __builtin_memcpy(&v, &u, 4);
    return make_float2((float)v[0], (float)v[1]);
}

// ================= degree / CSR build =================

// 1x edge stream; count atomics privatized into 8 slices (slice = blockIdx&7) ->
// each slice's hot window is ~400 KB and mostly L2-local. No shared cursors.
__global__ void k_deg_count(const int* __restrict__ col, int* __restrict__ cnt8, int E, int N) {
    int* cnt = cnt8 + (size_t)(blockIdx.x & 7) * N;
    const int eend = min(E, (blockIdx.x + 1) * FILL_CHUNK);
    for (int e = blockIdx.x * FILL_CHUNK + threadIdx.x; e < eend; e += 256)
        atomicAdd(&cnt[__builtin_nontemporal_load(col + e)], 1);
}

// sums the 8 count slices, emits dinv, then block-exclusive scan
__global__ void k_scan_block(const int* __restrict__ cnt8, int* __restrict__ excl,
                             int* __restrict__ bsum, float* __restrict__ dinv, int N) {
    __shared__ int s[256];
    int i = blockIdx.x * 256 + threadIdx.x;
    int v = 0;
    if (i < N) {
#pragma unroll
        for (int x = 0; x < 8; ++x) v += cnt8[(size_t)x * N + i];
        dinv[i] = 1.0f / sqrtf((float)(v + 1));   // +1 = self-loop
    }
    s[threadIdx.x] = v;
    __syncthreads();
    for (int off = 1; off < 256; off <<= 1) {
        int t = (threadIdx.x >= off) ? s[threadIdx.x - off] : 0;
        __syncthreads();
        s[threadIdx.x] += t;
        __syncthreads();
    }
    if (i < N) excl[i] = s[threadIdx.x] - v;
    if (threadIdx.x == 255) bsum[blockIdx.x] = s[255];
}

__global__ __launch_bounds__(1024) void k_scan_bsum(int* __restrict__ bsum, int nb) {
    __shared__ int s[1024];
    int i = threadIdx.x;
    int v = (i < nb) ? bsum[i] : 0;
    s[i] = v;
    __syncthreads();
    for (int off = 1; off < 1024; off <<= 1) {
        int t = (i >= off) ? s[i - off] : 0;
        __syncthreads();
        s[i] += t;
        __syncthreads();
    }
    if (i < nb) bsum[i] = s[i] - v;
}

__global__ void k_scan_add(int* __restrict__ row_ptr, const int* __restrict__ bsum,
                           int* __restrict__ fill, int N, int E) {
    int i = blockIdx.x * 256 + threadIdx.x;
    if (i < N) {
        int v = row_ptr[i] + bsum[blockIdx.x];
        row_ptr[i] = v;
        fill[i] = v;
    }
    if (i == 0) row_ptr[N] = E;
}

// XCD-range-filtered scatter (plain loads — NT loads regressed in R12).
// csr_src entry stored non-temporally: no write-allocate -> partial lines go
// out as sector writes instead of bouncing between XCD L2s.
__global__ void k_fill(const int* __restrict__ row, const int* __restrict__ col,
                       int* __restrict__ fill, int* __restrict__ csr_src, int E, int N) {
    const int xcd = blockIdx.x & 7;
    const int chunk = blockIdx.x >> 3;
    const int per = (N + 7) >> 3;
    const int lo = xcd * per;
    const int hi = min(N, lo + per);
    const int eend = min(E, (chunk + 1) * FILL_CHUNK);
    for (int e = chunk * FILL_CHUNK + threadIdx.x; e < eend; e += 256) {
        int c = col[e];
        if (c >= lo && c < hi) {
            int p = atomicAdd(&fill[c], 1);
            __builtin_nontemporal_store(row[e], csr_src + p);
        }
    }
}

// ================= W prep (all 3 layers, one launch) =================
// element (k,n) -> (k>>3)*1024 + n*8 + (k&7); hi [0,16384), lo [16384,32768)

__global__ void k_wprep3(const float* __restrict__ W0, const float* __restrict__ W1,
                         const float* __restrict__ W2, f16* __restrict__ out) {
    const int b = blockIdx.x;              // 48 blocks
    const int which = b >> 4;
    const float* W = which == 0 ? W0 : (which == 1 ? W1 : W2);
    f16* o = out + which * 32768;
    int i = (b & 15) * 256 + threadIdx.x;  // 4096 float4s
    int k = i >> 5, n0 = (i & 31) * 4;
    float4 v = reinterpret_cast<const float4*>(W)[i];
    float vv[4] = {v.x, v.y, v.z, v.w};
#pragma unroll
    for (int e = 0; e < 4; ++e) {
        int n = n0 + e;
        int idx = (k >> 3) * 1024 + n * 8 + (k & 7);
        f16 h = (f16)vv[e];
        o[idx] = h;
        o[16384 + idx] = (f16)(vv[e] - (float)h);
    }
}

// ================= GEMM: H16 = f16( dinv .* (X @ W) ) =================
// Swapped-operand MFMA: D = mfma(A=W^T-frag, B=X-frag); f16x4 epilogue stores.
// MODE 0: f32 input, 3 limbs, 64 KB LDS, swizzle at stage.
// MODE 1: f16 input PRE-SWIZZLED + PRE-RELU'd by agg -> linear 32 KB copy.

template<int MODE>
__global__ __launch_bounds__(512, 4) void k_gemm(const void* __restrict__ Xv,
                                                 const f16* __restrict__ Wt,
                                                 const float* __restrict__ dinv,
                                                 f16* __restrict__ H, int N) {
    __shared__ f16 Xs[MODE == 0 ? 2 * 16384 : 16384];
    const int t = threadIdx.x;
    const int row0 = blockIdx.x * BR;

    const int w  = t >> 6;
    const int l  = t & 63;
    const int lg = l >> 4;
    const int li = l & 15;
    const int ng = w & 3;           // 0..3 -> n-blocks ng*2, ng*2+1
    const int mg = w >> 2;          // 0..1 -> m-blocks mg*4 .. +3

    // W fragments (A operand), issued before X staging (latency hidden)
    f16x8 Wh[2][4], Wl[2][4];
#pragma unroll
    for (int nb = 0; nb < 2; ++nb) {
        const int ncol = (ng * 2 + nb) * 16 + li;
#pragma unroll
        for (int ks = 0; ks < 4; ++ks) {
            const int idx = (ks * 4 + lg) * 1024 + ncol * 8;
            Wh[nb][ks] = *reinterpret_cast<const f16x8*>(&Wt[idx]);
            Wl[nb][ks] = *reinterpret_cast<const f16x8*>(&Wt[16384 + idx]);
        }
    }

    if constexpr (MODE == 0) {
        const float* X = (const float*)Xv;
        for (int i = t; i < 4096; i += 512) {
            int r = i >> 5, q = i & 31;
            int gr = row0 + r;
            float4 v = make_float4(0.f, 0.f, 0.f, 0.f);
            if (gr < N) v = reinterpret_cast<const float4*>(X + (size_t)gr * HID)[q];
            f16 h0 = (f16)v.x, h1 = (f16)v.y, h2 = (f16)v.z, h3 = (f16)v.w;
            f16 l0 = (f16)(v.x - (float)h0), l1 = (f16)(v.y - (float)h1);
            f16 l2 = (f16)(v.z - (float)h2), l3 = (f16)(v.w - (float)h3);
            int base = r * 128 + (((q >> 1) ^ (r & 7)) * 8) + (q & 1) * 4;
            *reinterpret_cast<f16x4*>(&Xs[base])         = (f16x4){h0, h1, h2, h3};
            *reinterpret_cast<f16x4*>(&Xs[16384 + base]) = (f16x4){l0, l1, l2, l3};
        }
    } else {
        const f16* src = (const f16*)Xv + (size_t)row0 * HID;
        for (int i = t; i < 2048; i += 512)
            *reinterpret_cast<f16x8*>(&Xs[i * 8]) = *reinterpret_cast<const f16x8*>(src + (size_t)i * 8);
    }
    __syncthreads();

    f32x4 acc[2][4];
#pragma unroll
    for (int nb = 0; nb < 2; ++nb)
#pragma unroll
        for (int mb = 0; mb < 4; ++mb) acc[nb][mb] = (f32x4){0.f, 0.f, 0.f, 0.f};

#pragma unroll
    for (int mb = 0; mb < 4; ++mb) {
        const int arow = mg * 64 + mb * 16 + li;
#pragma unroll
        for (int ks = 0; ks < 4; ++ks) {
            const int idx = arow * 128 + (((ks * 4 + lg) ^ (arow & 7)) * 8);
            f16x8 Xh = *reinterpret_cast<const f16x8*>(&Xs[idx]);
#pragma unroll
            for (int nb = 0; nb < 2; ++nb) {
                acc[nb][mb] = __builtin_amdgcn_mfma_f32_16x16x32_f16(Wh[nb][ks], Xh, acc[nb][mb], 0, 0, 0);
                acc[nb][mb] = __builtin_amdgcn_mfma_f32_16x16x32_f16(Wl[nb][ks], Xh, acc[nb][mb], 0, 0, 0);
            }
            if constexpr (MODE == 0) {
                f16x8 Xl = *reinterpret_cast<const f16x8*>(&Xs[16384 + idx]);
#pragma unroll
                for (int nb = 0; nb < 2; ++nb)
                    acc[nb][mb] = __builtin_amdgcn_mfma_f32_16x16x32_f16(Wh[nb][ks], Xl, acc[nb][mb], 0, 0, 0);
            }
        }
    }

#pragma unroll
    for (int mb = 0; mb < 4; ++mb) {
        const int m = row0 + mg * 64 + mb * 16 + li;
        if (m < N) {
            const float d = dinv[m];
#pragma unroll
            for (int nb = 0; nb < 2; ++nb) {
                f16x4 o = {(f16)(acc[nb][mb][0] * d), (f16)(acc[nb][mb][1] * d),
                           (f16)(acc[nb][mb][2] * d), (f16)(acc[nb][mb][3] * d)};
                *reinterpret_cast<f16x4*>(&H[(size_t)m * HID + (ng * 2 + nb) * 16 + lg * 4]) = o;
            }
        }
    }
}

// ================= aggregation (row-gather, 2 nodes/wave, unroll 8) =================
// 32 lanes per node; lane owns uint2 (4 cols). F16OUT: store relu'd, LDS-swizzled
// f16 activation (consumed by gemm<1> as a linear copy); else plain f32 output.

template<bool F16OUT>
__global__ __launch_bounds__(256) void k_agg_csr(const f16* __restrict__ h,
                                                 const int* __restrict__ csr_src,
                                                 const int* __restrict__ row_ptr,
                                                 const float* __restrict__ dinv,
                                                 const float* __restrict__ bias,
                                                 void* __restrict__ outv, int N) {
    const int node = blockIdx.x * 8 + (threadIdx.x >> 5);
    if (node >= N) return;
    const int l = threadIdx.x & 31;
    const uint2* h2 = reinterpret_cast<const uint2*>(h);   // row = 32 uint2

    uint2 us = h2[(size_t)node * 32 + l];
    float2 a0 = h2f(us.x), a1 = h2f(us.y);
    float acc0 = a0.x, acc1 = a0.y, acc2 = a1.x, acc3 = a1.y;

    int j = row_ptr[node];
    const int end = row_ptr[node + 1];

    for (; j + 8 <= end; j += 8) {
        int s0 = csr_src[j];
        int s1 = csr_src[j + 1];
        int s2 = csr_src[j + 2];
        int s3 = csr_src[j + 3];
        int s4 = csr_src[j + 4];
        int s5 = csr_src[j + 5];
        int s6 = csr_src[j + 6];
        int s7 = csr_src[j + 7];
        uint2 u0 = h2[(size_t)s0 * 32 + l];
        uint2 u1 = h2[(size_t)s1 * 32 + l];
        uint2 u2 = h2[(size_t)s2 * 32 + l];
        uint2 u3 = h2[(size_t)s3 * 32 + l];
        uint2 u4 = h2[(size_t)s4 * 32 + l];
        uint2 u5 = h2[(size_t)s5 * 32 + l];
        uint2 u6 = h2[(size_t)s6 * 32 + l];
        uint2 u7 = h2[(size_t)s7 * 32 + l];
        float2 v0 = h2f(u0.x), w0 = h2f(u0.y), v1 = h2f(u1.x), w1 = h2f(u1.y);
        float2 v2 = h2f(u2.x), w2 = h2f(u2.y), v3 = h2f(u3.x), w3 = h2f(u3.y);
        float2 v4 = h2f(u4.x), w4 = h2f(u4.y), v5 = h2f(u5.x), w5 = h2f(u5.y);
        float2 v6 = h2f(u6.x), w6 = h2f(u6.y), v7 = h2f(u7.x), w7 = h2f(u7.y);
        acc0 += ((v0.x + v1.x) + (v2.x + v3.x)) + ((v4.x + v5.x) + (v6.x + v7.x));
        acc1 += ((v0.y + v1.y) + (v2.y + v3.y)) + ((v4.y + v5.y) + (v6.y + v7.y));
        acc2 += ((w0.x + w1.x) + (w2.x + w3.x)) + ((w4.x + w5.x) + (w6.x + w7.x));
        acc3 += ((w0.y + w1.y) + (w2.y + w3.y)) + ((w4.y + w5.y) + (w6.y + w7.y));
    }
    for (; j < end; ++j) {
        uint2 u = h2[(size_t)csr_src[j] * 32 + l];
        float2 v = h2f(u.x), w = h2f(u.y);
        acc0 += v.x; acc1 += v.y; acc2 += w.x; acc3 += w.y;
    }

    const float di = dinv[node];
    const float4 bv = reinterpret_cast<const float4*>(bias)[l];
    float o0 = fmaf(di, acc0, bv.x);
    float o1 = fmaf(di, acc1, bv.y);
    float o2 = fmaf(di, acc2, bv.z);
    float o3 = fmaf(di, acc3, bv.w);

    if constexpr (F16OUT) {
        o0 = fmaxf(o0, 0.f); o1 = fmaxf(o1, 0.f);
        o2 = fmaxf(o2, 0.f); o3 = fmaxf(o3, 0.f);
        const int swz = (((l >> 1) ^ (node & 7)) << 1) | (l & 1);
        f16x4 o = {(f16)o0, (f16)o1, (f16)o2, (f16)o3};
        *reinterpret_cast<f16x4*>((f16*)outv + (size_t)node * HID + swz * 4) = o;
    } else {
        *reinterpret_cast<float4*>((float*)outv + (size_t)node * HID + l * 4) =
            make_float4(o0, o1, o2, o3);
    }
}

// ================= launch =================

extern "C" void kernel_launch(void* const* d_in, const int* in_sizes, int n_in,
                              void* d_out, int out_size, void* d_ws, size_t ws_size,
                              hipStream_t stream) {
    const float* x  = (const float*)d_in[0];
    const int*   ei = (const int*)  d_in[1];
    const float* W0 = (const float*)d_in[2];
    const float* b0 = (const float*)d_in[3];
    const float* W1 = (const float*)d_in[4];
    const float* b1 = (const float*)d_in[5];
    const float* W2 = (const float*)d_in[6];
    const float* b2 = (const float*)d_in[7];

    const int N = in_sizes[0] / HID;
    const int E = in_sizes[1] / 2;
    const int* row = ei;        // sources
    const int* col = ei + E;    // destinations

    const int nb_n = (N + 255) / 256;

    // workspace layout
    f16*   h16     = (f16*)d_ws;                      // [N,128] f16 (= h', dinv-scaled)
    float* dinv    = (float*)(h16 + (size_t)N * HID); // [N]
    int*   cnt8    = (int*)(dinv + N);                // [8][N]
    int*   row_ptr = cnt8 + (size_t)8 * N;            // [N+1]
    int*   fill    = row_ptr + (N + 1);               // [N]
    int*   bsum    = fill + N;                        // [nb_n]
    int*   csr_src = bsum + nb_n;                     // [E]
    f16*   wt      = (f16*)(csr_src + E);             // [3*32768]
    f16*   wt0     = wt;
    f16*   wt1     = wt + 32768;
    f16*   wt2     = wt + 65536;
    f16*   act     = (f16*)d_out;                     // layers 0,1 activation (f16, swizzled, relu'd)
    float* out     = (float*)d_out;                   // final f32 output

    const int nb_gemm  = (N + BR - 1) / BR;
    const int nb_agg   = (N + 7) / 8;                 // 2 nodes per wave
    const int nb_chunk = (E + FILL_CHUNK - 1) / FILL_CHUNK;
    const int nb_fill  = nb_chunk * 8;

    // ---- CSR build + W prep ----
    (void)hipMemsetAsync(cnt8, 0, (size_t)8 * N * sizeof(int), stream);
    k_wprep3<<<48, 256, 0, stream>>>(W0, W1, W2, wt);
    k_deg_count <<<nb_chunk, 256, 0, stream>>>(col, cnt8, E, N);
    k_scan_block<<<nb_n, 256, 0, stream>>>(cnt8, row_ptr, bsum, dinv, N);
    k_scan_bsum <<<1, 1024, 0, stream>>>(bsum, nb_n);
    k_scan_add  <<<nb_n, 256, 0, stream>>>(row_ptr, bsum, fill, N, E);
    k_fill      <<<nb_fill, 256, 0, stream>>>(row, col, fill, csr_src, E, N);

    // ---- layer 0: x (f32) -> h16 -> act (f16, swizzled+relu) ----
    k_gemm<0>      <<<nb_gemm, 512, 0, stream>>>(x, wt0, dinv, h16, N);
    k_agg_csr<true><<<nb_agg, 256, 0, stream>>>(h16, csr_src, row_ptr, dinv, b0, act, N);
    // ---- layer 1: act -> h16 -> act ----
    k_gemm<1>      <<<nb_gemm, 512, 0, stream>>>(act, wt1, dinv, h16, N);
    k_agg_csr<true><<<nb_agg, 256, 0, stream>>>(h16, csr_src, row_ptr, dinv, b1, act, N);
    // ---- layer 2: act -> h16 -> out (f32) ----
    k_gemm<1>      <<<nb_gemm, 512, 0, stream>>>(act, wt2, dinv, h16, N);
    k_agg_csr<false><<<nb_agg, 256, 0, stream>>>(h16, csr_src, row_ptr, dinv, b2, out, N);
}

// Round 16
// 418.907 us; speedup vs baseline: 6.6980x; 1.0125x over previous
//
#include <hip/hip_runtime.h>

#define HID 128
#define BR  128        // GEMM rows per block
#define FILL_CHUNK 2048

typedef _Float16 f16;
typedef f16 f16x2 __attribute__((ext_vector_type(2)));
typedef f16 f16x4 __attribute__((ext_vector_type(4)));
typedef f16 f16x8 __attribute__((ext_vector_type(8)));
typedef float f32x4 __attribute__((ext_vector_type(4)));

static __device__ __forceinline__ float2 h2f(unsigned int u) {
    f16x2 v;
    __builtin_memcpy(&v, &u, 4);
    return make_float2((float)v[0], (float)v[1]);
}

// ================= degree / CSR build =================

// 1x edge stream; count atomics privatized into 8 slices (slice = blockIdx&7) ->
// each slice's hot window is ~400 KB and mostly L2-local. No shared cursors.
__global__ void k_deg_count(const int* __restrict__ col, int* __restrict__ cnt8, int E, int N) {
    int* cnt = cnt8 + (size_t)(blockIdx.x & 7) * N;
    const int eend = min(E, (blockIdx.x + 1) * FILL_CHUNK);
    for (int e = blockIdx.x * FILL_CHUNK + threadIdx.x; e < eend; e += 256)
        atomicAdd(&cnt[__builtin_nontemporal_load(col + e)], 1);
}

// sums the 8 count slices, emits dinv, then block-exclusive scan
__global__ void k_scan_block(const int* __restrict__ cnt8, int* __restrict__ excl,
                             int* __restrict__ bsum, float* __restrict__ dinv, int N) {
    __shared__ int s[256];
    int i = blockIdx.x * 256 + threadIdx.x;
    int v = 0;
    if (i < N) {
#pragma unroll
        for (int x = 0; x < 8; ++x) v += cnt8[(size_t)x * N + i];
        dinv[i] = 1.0f / sqrtf((float)(v + 1));   // +1 = self-loop
    }
    s[threadIdx.x] = v;
    __syncthreads();
    for (int off = 1; off < 256; off <<= 1) {
        int t = (threadIdx.x >= off) ? s[threadIdx.x - off] : 0;
        __syncthreads();
        s[threadIdx.x] += t;
        __syncthreads();
    }
    if (i < N) excl[i] = s[threadIdx.x] - v;
    if (threadIdx.x == 255) bsum[blockIdx.x] = s[255];
}

__global__ __launch_bounds__(1024) void k_scan_bsum(int* __restrict__ bsum, int nb) {
    __shared__ int s[1024];
    int i = threadIdx.x;
    int v = (i < nb) ? bsum[i] : 0;
    s[i] = v;
    __syncthreads();
    for (int off = 1; off < 1024; off <<= 1) {
        int t = (i >= off) ? s[i - off] : 0;
        __syncthreads();
        s[i] += t;
        __syncthreads();
    }
    if (i < nb) bsum[i] = s[i] - v;
}

__global__ void k_scan_add(int* __restrict__ row_ptr, const int* __restrict__ bsum,
                           int* __restrict__ fill, int N, int E) {
    int i = blockIdx.x * 256 + threadIdx.x;
    if (i < N) {
        int v = row_ptr[i] + bsum[blockIdx.x];
        row_ptr[i] = v;
        fill[i] = v;
    }
    if (i == 0) row_ptr[N] = E;
}

// XCD-range-filtered scatter. Plain loads and plain stores (NT loads regressed
// in R12 [+7us], NT stores regressed in R15 [WRITE 67->121 MB]).
__global__ void k_fill(const int* __restrict__ row, const int* __restrict__ col,
                       int* __restrict__ fill, int* __restrict__ csr_src, int E, int N) {
    const int xcd = blockIdx.x & 7;
    const int chunk = blockIdx.x >> 3;
    const int per = (N + 7) >> 3;
    const int lo = xcd * per;
    const int hi = min(N, lo + per);
    const int eend = min(E, (chunk + 1) * FILL_CHUNK);
    for (int e = chunk * FILL_CHUNK + threadIdx.x; e < eend; e += 256) {
        int c = col[e];
        if (c >= lo && c < hi) {
            int p = atomicAdd(&fill[c], 1);
            csr_src[p] = row[e];
        }
    }
}

// ================= W prep (all 3 layers, one launch) =================
// element (k,n) -> (k>>3)*1024 + n*8 + (k&7); hi [0,16384), lo [16384,32768)

__global__ void k_wprep3(const float* __restrict__ W0, const float* __restrict__ W1,
                         const float* __restrict__ W2, f16* __restrict__ out) {
    const int b = blockIdx.x;              // 48 blocks
    const int which = b >> 4;
    const float* W = which == 0 ? W0 : (which == 1 ? W1 : W2);
    f16* o = out + which * 32768;
    int i = (b & 15) * 256 + threadIdx.x;  // 4096 float4s
    int k = i >> 5, n0 = (i & 31) * 4;
    float4 v = reinterpret_cast<const float4*>(W)[i];
    float vv[4] = {v.x, v.y, v.z, v.w};
#pragma unroll
    for (int e = 0; e < 4; ++e) {
        int n = n0 + e;
        int idx = (k >> 3) * 1024 + n * 8 + (k & 7);
        f16 h = (f16)vv[e];
        o[idx] = h;
        o[16384 + idx] = (f16)(vv[e] - (float)h);
    }
}

// ================= GEMM: H16 = f16( dinv .* (X @ W) ) =================
// Swapped-operand MFMA: D = mfma(A=W^T-frag, B=X-frag); f16x4 epilogue stores.
// 2 limbs everywhere: X(f16) * (Wh + Wl). Since H is STORED as f16 (2^-11 rel
// rounding regardless), the 3rd limb (xl*Wh) only adds precision below the
// storage rounding — dropped. 32 KB LDS in both modes -> 4 blocks/CU.
// MODE 0: f32 input, convert hi-f16 at stage + swizzle.
// MODE 1: f16 input PRE-SWIZZLED + PRE-RELU'd by agg -> linear 32 KB copy.

template<int MODE>
__global__ __launch_bounds__(512, 4) void k_gemm(const void* __restrict__ Xv,
                                                 const f16* __restrict__ Wt,
                                                 const float* __restrict__ dinv,
                                                 f16* __restrict__ H, int N) {
    __shared__ f16 Xs[16384];   // 32 KB
    const int t = threadIdx.x;
    const int row0 = blockIdx.x * BR;

    const int w  = t >> 6;
    const int l  = t & 63;
    const int lg = l >> 4;
    const int li = l & 15;
    const int ng = w & 3;           // 0..3 -> n-blocks ng*2, ng*2+1
    const int mg = w >> 2;          // 0..1 -> m-blocks mg*4 .. +3

    // W fragments (A operand), issued before X staging (latency hidden)
    f16x8 Wh[2][4], Wl[2][4];
#pragma unroll
    for (int nb = 0; nb < 2; ++nb) {
        const int ncol = (ng * 2 + nb) * 16 + li;
#pragma unroll
        for (int ks = 0; ks < 4; ++ks) {
            const int idx = (ks * 4 + lg) * 1024 + ncol * 8;
            Wh[nb][ks] = *reinterpret_cast<const f16x8*>(&Wt[idx]);
            Wl[nb][ks] = *reinterpret_cast<const f16x8*>(&Wt[16384 + idx]);
        }
    }

    if constexpr (MODE == 0) {
        // f32 input: convert to f16 (hi), 16B-chunk swizzle
        const float* X = (const float*)Xv;
        for (int i = t; i < 4096; i += 512) {
            int r = i >> 5, q = i & 31;
            int gr = row0 + r;
            float4 v = make_float4(0.f, 0.f, 0.f, 0.f);
            if (gr < N) v = reinterpret_cast<const float4*>(X + (size_t)gr * HID)[q];
            int base = r * 128 + (((q >> 1) ^ (r & 7)) * 8) + (q & 1) * 4;
            *reinterpret_cast<f16x4*>(&Xs[base]) =
                (f16x4){(f16)v.x, (f16)v.y, (f16)v.z, (f16)v.w};
        }
    } else {
        // f16 input already relu'd + swizzled: straight 32 KB copy
        const f16* src = (const f16*)Xv + (size_t)row0 * HID;
        for (int i = t; i < 2048; i += 512)
            *reinterpret_cast<f16x8*>(&Xs[i * 8]) = *reinterpret_cast<const f16x8*>(src + (size_t)i * 8);
    }
    __syncthreads();

    f32x4 acc[2][4];
#pragma unroll
    for (int nb = 0; nb < 2; ++nb)
#pragma unroll
        for (int mb = 0; mb < 4; ++mb) acc[nb][mb] = (f32x4){0.f, 0.f, 0.f, 0.f};

#pragma unroll
    for (int mb = 0; mb < 4; ++mb) {
        const int arow = mg * 64 + mb * 16 + li;
#pragma unroll
        for (int ks = 0; ks < 4; ++ks) {
            const int idx = arow * 128 + (((ks * 4 + lg) ^ (arow & 7)) * 8);
            f16x8 Xh = *reinterpret_cast<const f16x8*>(&Xs[idx]);
#pragma unroll
            for (int nb = 0; nb < 2; ++nb) {
                acc[nb][mb] = __builtin_amdgcn_mfma_f32_16x16x32_f16(Wh[nb][ks], Xh, acc[nb][mb], 0, 0, 0);
                acc[nb][mb] = __builtin_amdgcn_mfma_f32_16x16x32_f16(Wl[nb][ks], Xh, acc[nb][mb], 0, 0, 0);
            }
        }
    }

    // epilogue: D col(lane&15) = m-offset, row(lg*4+reg) = n-offset -> f16x4 stores
#pragma unroll
    for (int mb = 0; mb < 4; ++mb) {
        const int m = row0 + mg * 64 + mb * 16 + li;
        if (m < N) {
            const float d = dinv[m];
#pragma unroll
            for (int nb = 0; nb < 2; ++nb) {
                f16x4 o = {(f16)(acc[nb][mb][0] * d), (f16)(acc[nb][mb][1] * d),
                           (f16)(acc[nb][mb][2] * d), (f16)(acc[nb][mb][3] * d)};
                *reinterpret_cast<f16x4*>(&H[(size_t)m * HID + (ng * 2 + nb) * 16 + lg * 4]) = o;
            }
        }
    }
}

// ================= aggregation (row-gather, 2 nodes/wave, unroll 8) =================
// 32 lanes per node; lane owns uint2 (4 cols). F16OUT: store relu'd, LDS-swizzled
// f16 activation (consumed by gemm<1> as a linear copy); else plain f32 output.

template<bool F16OUT>
__global__ __launch_bounds__(256) void k_agg_csr(const f16* __restrict__ h,
                                                 const int* __restrict__ csr_src,
                                                 const int* __restrict__ row_ptr,
                                                 const float* __restrict__ dinv,
                                                 const float* __restrict__ bias,
                                                 void* __restrict__ outv, int N) {
    const int node = blockIdx.x * 8 + (threadIdx.x >> 5);
    if (node >= N) return;
    const int l = threadIdx.x & 31;
    const uint2* h2 = reinterpret_cast<const uint2*>(h);   // row = 32 uint2

    uint2 us = h2[(size_t)node * 32 + l];
    float2 a0 = h2f(us.x), a1 = h2f(us.y);
    float acc0 = a0.x, acc1 = a0.y, acc2 = a1.x, acc3 = a1.y;

    int j = row_ptr[node];
    const int end = row_ptr[node + 1];

    for (; j + 8 <= end; j += 8) {
        int s0 = csr_src[j];
        int s1 = csr_src[j + 1];
        int s2 = csr_src[j + 2];
        int s3 = csr_src[j + 3];
        int s4 = csr_src[j + 4];
        int s5 = csr_src[j + 5];
        int s6 = csr_src[j + 6];
        int s7 = csr_src[j + 7];
        uint2 u0 = h2[(size_t)s0 * 32 + l];
        uint2 u1 = h2[(size_t)s1 * 32 + l];
        uint2 u2 = h2[(size_t)s2 * 32 + l];
        uint2 u3 = h2[(size_t)s3 * 32 + l];
        uint2 u4 = h2[(size_t)s4 * 32 + l];
        uint2 u5 = h2[(size_t)s5 * 32 + l];
        uint2 u6 = h2[(size_t)s6 * 32 + l];
        uint2 u7 = h2[(size_t)s7 * 32 + l];
        float2 v0 = h2f(u0.x), w0 = h2f(u0.y), v1 = h2f(u1.x), w1 = h2f(u1.y);
        float2 v2 = h2f(u2.x), w2 = h2f(u2.y), v3 = h2f(u3.x), w3 = h2f(u3.y);
        float2 v4 = h2f(u4.x), w4 = h2f(u4.y), v5 = h2f(u5.x), w5 = h2f(u5.y);
        float2 v6 = h2f(u6.x), w6 = h2f(u6.y), v7 = h2f(u7.x), w7 = h2f(u7.y);
        acc0 += ((v0.x + v1.x) + (v2.x + v3.x)) + ((v4.x + v5.x) + (v6.x + v7.x));
        acc1 += ((v0.y + v1.y) + (v2.y + v3.y)) + ((v4.y + v5.y) + (v6.y + v7.y));
        acc2 += ((w0.x + w1.x) + (w2.x + w3.x)) + ((w4.x + w5.x) + (w6.x + w7.x));
        acc3 += ((w0.y + w1.y) + (w2.y + w3.y)) + ((w4.y + w5.y) + (w6.y + w7.y));
    }
    for (; j < end; ++j) {
        uint2 u = h2[(size_t)csr_src[j] * 32 + l];
        float2 v = h2f(u.x), w = h2f(u.y);
        acc0 += v.x; acc1 += v.y; acc2 += w.x; acc3 += w.y;
    }

    const float di = dinv[node];
    const float4 bv = reinterpret_cast<const float4*>(bias)[l];
    float o0 = fmaf(di, acc0, bv.x);
    float o1 = fmaf(di, acc1, bv.y);
    float o2 = fmaf(di, acc2, bv.z);
    float o3 = fmaf(di, acc3, bv.w);

    if constexpr (F16OUT) {
        o0 = fmaxf(o0, 0.f); o1 = fmaxf(o1, 0.f);
        o2 = fmaxf(o2, 0.f); o3 = fmaxf(o3, 0.f);
        const int swz = (((l >> 1) ^ (node & 7)) << 1) | (l & 1);
        f16x4 o = {(f16)o0, (f16)o1, (f16)o2, (f16)o3};
        *reinterpret_cast<f16x4*>((f16*)outv + (size_t)node * HID + swz * 4) = o;
    } else {
        *reinterpret_cast<float4*>((float*)outv + (size_t)node * HID + l * 4) =
            make_float4(o0, o1, o2, o3);
    }
}

// ================= launch =================

extern "C" void kernel_launch(void* const* d_in, const int* in_sizes, int n_in,
                              void* d_out, int out_size, void* d_ws, size_t ws_size,
                              hipStream_t stream) {
    const float* x  = (const float*)d_in[0];
    const int*   ei = (const int*)  d_in[1];
    const float* W0 = (const float*)d_in[2];
    const float* b0 = (const float*)d_in[3];
    const float* W1 = (const float*)d_in[4];
    const float* b1 = (const float*)d_in[5];
    const float* W2 = (const float*)d_in[6];
    const float* b2 = (const float*)d_in[7];

    const int N = in_sizes[0] / HID;
    const int E = in_sizes[1] / 2;
    const int* row = ei;        // sources
    const int* col = ei + E;    // destinations

    const int nb_n = (N + 255) / 256;

    // workspace layout
    f16*   h16     = (f16*)d_ws;                      // [N,128] f16 (= h', dinv-scaled)
    float* dinv    = (float*)(h16 + (size_t)N * HID); // [N]
    int*   cnt8    = (int*)(dinv + N);                // [8][N]
    int*   row_ptr = cnt8 + (size_t)8 * N;            // [N+1]
    int*   fill    = row_ptr + (N + 1);               // [N]
    int*   bsum    = fill + N;                        // [nb_n]
    int*   csr_src = bsum + nb_n;                     // [E]
    f16*   wt      = (f16*)(csr_src + E);             // [3*32768]
    f16*   wt0     = wt;
    f16*   wt1     = wt + 32768;
    f16*   wt2     = wt + 65536;
    f16*   act     = (f16*)d_out;                     // layers 0,1 activation (f16, swizzled, relu'd)
    float* out     = (float*)d_out;                   // final f32 output

    const int nb_gemm  = (N + BR - 1) / BR;
    const int nb_agg   = (N + 7) / 8;                 // 2 nodes per wave
    const int nb_chunk = (E + FILL_CHUNK - 1) / FILL_CHUNK;
    const int nb_fill  = nb_chunk * 8;

    // ---- CSR build + W prep ----
    (void)hipMemsetAsync(cnt8, 0, (size_t)8 * N * sizeof(int), stream);
    k_wprep3<<<48, 256, 0, stream>>>(W0, W1, W2, wt);
    k_deg_count <<<nb_chunk, 256, 0, stream>>>(col, cnt8, E, N);
    k_scan_block<<<nb_n, 256, 0, stream>>>(cnt8, row_ptr, bsum, dinv, N);
    k_scan_bsum <<<1, 1024, 0, stream>>>(bsum, nb_n);
    k_scan_add  <<<nb_n, 256, 0, stream>>>(row_ptr, bsum, fill, N, E);
    k_fill      <<<nb_fill, 256, 0, stream>>>(row, col, fill, csr_src, E, N);

    // ---- layer 0: x (f32) -> h16 -> act (f16, swizzled+relu) ----
    k_gemm<0>      <<<nb_gemm, 512, 0, stream>>>(x, wt0, dinv, h16, N);
    k_agg_csr<true><<<nb_agg, 256, 0, stream>>>(h16, csr_src, row_ptr, dinv, b0, act, N);
    // ---- layer 1: act -> h16 -> act ----
    k_gemm<1>      <<<nb_gemm, 512, 0, stream>>>(act, wt1, dinv, h16, N);
    k_agg_csr<true><<<nb_agg, 256, 0, stream>>>(h16, csr_src, row_ptr, dinv, b1, act, N);
    // ---- layer 2: act -> h16 -> out (f32) ----
    k_gemm<1>      <<<nb_gemm, 512, 0, stream>>>(act, wt2, dinv, h16, N);
    k_agg_csr<false><<<nb_agg, 256, 0, stream>>>(h16, csr_src, row_ptr, dinv, b2, out, N);
}

// Round 17
// 412.075 us; speedup vs baseline: 6.8090x; 1.0166x over previous
//
#include <hip/hip_runtime.h>

#define HID 128
#define BR  128        // GEMM rows per block
#define FILL_CHUNK 2048

typedef _Float16 f16;
typedef f16 f16x2 __attribute__((ext_vector_type(2)));
typedef f16 f16x4 __attribute__((ext_vector_type(4)));
typedef f16 f16x8 __attribute__((ext_vector_type(8)));
typedef float f32x4 __attribute__((ext_vector_type(4)));

static __device__ __forceinline__ float2 h2f(unsigned int u) {
    f16x2 v;
    __builtin_memcpy(&v, &u, 4);
    return make_float2((float)v[0], (float)v[1]);
}

// ================= fused W-prep + degree count (one launch) =================
// Blocks [0,48): W transpose + f16 hi/lo split. Blocks [48,..): degree count,
// atomics privatized into 8 slices (slice = blockIdx&7, ~400 KB hot window).

__global__ void k_prep_count(const float* __restrict__ W0, const float* __restrict__ W1,
                             const float* __restrict__ W2, f16* __restrict__ wt,
                             const int* __restrict__ col, int* __restrict__ cnt8,
                             int E, int N) {
    if (blockIdx.x < 48) {
        const int b = blockIdx.x;
        const int which = b >> 4;
        const float* W = which == 0 ? W0 : (which == 1 ? W1 : W2);
        f16* o = wt + which * 32768;
        int i = (b & 15) * 256 + threadIdx.x;  // 4096 float4s
        int k = i >> 5, n0 = (i & 31) * 4;
        float4 v = reinterpret_cast<const float4*>(W)[i];
        float vv[4] = {v.x, v.y, v.z, v.w};
#pragma unroll
        for (int e = 0; e < 4; ++e) {
            int n = n0 + e;
            int idx = (k >> 3) * 1024 + n * 8 + (k & 7);
            f16 h = (f16)vv[e];
            o[idx] = h;
            o[16384 + idx] = (f16)(vv[e] - (float)h);
        }
    } else {
        const int bb = blockIdx.x - 48;
        int* cnt = cnt8 + (size_t)(bb & 7) * N;
        const int eend = min(E, (bb + 1) * FILL_CHUNK);
        for (int e = bb * FILL_CHUNK + threadIdx.x; e < eend; e += 256)
            atomicAdd(&cnt[__builtin_nontemporal_load(col + e)], 1);
    }
}

// sums the 8 count slices, emits dinv, then block-exclusive scan
__global__ void k_scan_block(const int* __restrict__ cnt8, int* __restrict__ excl,
                             int* __restrict__ bsum, float* __restrict__ dinv, int N) {
    __shared__ int s[256];
    int i = blockIdx.x * 256 + threadIdx.x;
    int v = 0;
    if (i < N) {
#pragma unroll
        for (int x = 0; x < 8; ++x) v += cnt8[(size_t)x * N + i];
        dinv[i] = 1.0f / sqrtf((float)(v + 1));   // +1 = self-loop
    }
    s[threadIdx.x] = v;
    __syncthreads();
    for (int off = 1; off < 256; off <<= 1) {
        int t = (threadIdx.x >= off) ? s[threadIdx.x - off] : 0;
        __syncthreads();
        s[threadIdx.x] += t;
        __syncthreads();
    }
    if (i < N) excl[i] = s[threadIdx.x] - v;
    if (threadIdx.x == 255) bsum[blockIdx.x] = s[255];
}

__global__ __launch_bounds__(1024) void k_scan_bsum(int* __restrict__ bsum, int nb) {
    __shared__ int s[1024];
    int i = threadIdx.x;
    int v = (i < nb) ? bsum[i] : 0;
    s[i] = v;
    __syncthreads();
    for (int off = 1; off < 1024; off <<= 1) {
        int t = (i >= off) ? s[i - off] : 0;
        __syncthreads();
        s[i] += t;
        __syncthreads();
    }
    if (i < nb) bsum[i] = s[i] - v;
}

__global__ void k_scan_add(int* __restrict__ row_ptr, const int* __restrict__ bsum,
                           int* __restrict__ fill, int N, int E) {
    int i = blockIdx.x * 256 + threadIdx.x;
    if (i < N) {
        int v = row_ptr[i] + bsum[blockIdx.x];
        row_ptr[i] = v;
        fill[i] = v;
    }
    if (i == 0) row_ptr[N] = E;
}

// Range-filtered scatter, 4 windows (halves the col re-stream vs 8; WRITE_SIZE
// will tell whether the 2-XCDs-per-window bounce costs more than the saved stream).
__global__ void k_fill(const int* __restrict__ row, const int* __restrict__ col,
                       int* __restrict__ fill, int* __restrict__ csr_src, int E, int N) {
    const int win = blockIdx.x & 3;
    const int chunk = blockIdx.x >> 2;
    const int per = (N + 3) >> 2;
    const int lo = win * per;
    const int hi = min(N, lo + per);
    const int eend = min(E, (chunk + 1) * FILL_CHUNK);
    for (int e = chunk * FILL_CHUNK + threadIdx.x; e < eend; e += 256) {
        int c = col[e];
        if (c >= lo && c < hi) {
            int p = atomicAdd(&fill[c], 1);
            csr_src[p] = row[e];
        }
    }
}

// ================= GEMM: H16 = f16( dinv .* (X @ W) ) =================
// Swapped-operand MFMA: D = mfma(A=W^T-frag, B=X-frag); f16x4 epilogue stores.
// 2 limbs: X(f16) * (Wh + Wl); 32 KB LDS -> 4 blocks/CU.
// MODE 0: f32 input, convert hi-f16 at stage + swizzle.
// MODE 1: f16 input PRE-SWIZZLED + PRE-RELU'd by agg -> linear 32 KB copy.

template<int MODE>
__global__ __launch_bounds__(512, 4) void k_gemm(const void* __restrict__ Xv,
                                                 const f16* __restrict__ Wt,
                                                 const float* __restrict__ dinv,
                                                 f16* __restrict__ H, int N) {
    __shared__ f16 Xs[16384];   // 32 KB
    const int t = threadIdx.x;
    const int row0 = blockIdx.x * BR;

    const int w  = t >> 6;
    const int l  = t & 63;
    const int lg = l >> 4;
    const int li = l & 15;
    const int ng = w & 3;           // 0..3 -> n-blocks ng*2, ng*2+1
    const int mg = w >> 2;          // 0..1 -> m-blocks mg*4 .. +3

    // W fragments (A operand), issued before X staging (latency hidden)
    f16x8 Wh[2][4], Wl[2][4];
#pragma unroll
    for (int nb = 0; nb < 2; ++nb) {
        const int ncol = (ng * 2 + nb) * 16 + li;
#pragma unroll
        for (int ks = 0; ks < 4; ++ks) {
            const int idx = (ks * 4 + lg) * 1024 + ncol * 8;
            Wh[nb][ks] = *reinterpret_cast<const f16x8*>(&Wt[idx]);
            Wl[nb][ks] = *reinterpret_cast<const f16x8*>(&Wt[16384 + idx]);
        }
    }

    if constexpr (MODE == 0) {
        const float* X = (const float*)Xv;
        for (int i = t; i < 4096; i += 512) {
            int r = i >> 5, q = i & 31;
            int gr = row0 + r;
            float4 v = make_float4(0.f, 0.f, 0.f, 0.f);
            if (gr < N) v = reinterpret_cast<const float4*>(X + (size_t)gr * HID)[q];
            int base = r * 128 + (((q >> 1) ^ (r & 7)) * 8) + (q & 1) * 4;
            *reinterpret_cast<f16x4*>(&Xs[base]) =
                (f16x4){(f16)v.x, (f16)v.y, (f16)v.z, (f16)v.w};
        }
    } else {
        const f16* src = (const f16*)Xv + (size_t)row0 * HID;
        for (int i = t; i < 2048; i += 512)
            *reinterpret_cast<f16x8*>(&Xs[i * 8]) = *reinterpret_cast<const f16x8*>(src + (size_t)i * 8);
    }
    __syncthreads();

    f32x4 acc[2][4];
#pragma unroll
    for (int nb = 0; nb < 2; ++nb)
#pragma unroll
        for (int mb = 0; mb < 4; ++mb) acc[nb][mb] = (f32x4){0.f, 0.f, 0.f, 0.f};

#pragma unroll
    for (int mb = 0; mb < 4; ++mb) {
        const int arow = mg * 64 + mb * 16 + li;
#pragma unroll
        for (int ks = 0; ks < 4; ++ks) {
            const int idx = arow * 128 + (((ks * 4 + lg) ^ (arow & 7)) * 8);
            f16x8 Xh = *reinterpret_cast<const f16x8*>(&Xs[idx]);
#pragma unroll
            for (int nb = 0; nb < 2; ++nb) {
                acc[nb][mb] = __builtin_amdgcn_mfma_f32_16x16x32_f16(Wh[nb][ks], Xh, acc[nb][mb], 0, 0, 0);
                acc[nb][mb] = __builtin_amdgcn_mfma_f32_16x16x32_f16(Wl[nb][ks], Xh, acc[nb][mb], 0, 0, 0);
            }
        }
    }

    // epilogue: D col(lane&15) = m-offset, row(lg*4+reg) = n-offset -> f16x4 stores
#pragma unroll
    for (int mb = 0; mb < 4; ++mb) {
        const int m = row0 + mg * 64 + mb * 16 + li;
        if (m < N) {
            const float d = dinv[m];
#pragma unroll
            for (int nb = 0; nb < 2; ++nb) {
                f16x4 o = {(f16)(acc[nb][mb][0] * d), (f16)(acc[nb][mb][1] * d),
                           (f16)(acc[nb][mb][2] * d), (f16)(acc[nb][mb][3] * d)};
                *reinterpret_cast<f16x4*>(&H[(size_t)m * HID + (ng * 2 + nb) * 16 + lg * 4]) = o;
            }
        }
    }
}

// ================= aggregation (row-gather, 2 nodes/wave, idx-prefetch) =================
// 32 lanes per node; lane owns uint2 (4 cols). Batch b+1's csr_src index loads
// are issued BEFORE batch b's gathers complete -> index latency hides under the
// gather wait. F16OUT: store relu'd, LDS-swizzled f16 activation; else f32 out.

template<bool F16OUT>
__global__ __launch_bounds__(256) void k_agg_csr(const f16* __restrict__ h,
                                                 const int* __restrict__ csr_src,
                                                 const int* __restrict__ row_ptr,
                                                 const float* __restrict__ dinv,
                                                 const float* __restrict__ bias,
                                                 void* __restrict__ outv, int N) {
    const int node = blockIdx.x * 8 + (threadIdx.x >> 5);
    if (node >= N) return;
    const int l = threadIdx.x & 31;
    const uint2* h2 = reinterpret_cast<const uint2*>(h);   // row = 32 uint2

    uint2 us = h2[(size_t)node * 32 + l];
    float2 a0 = h2f(us.x), a1 = h2f(us.y);
    float acc0 = a0.x, acc1 = a0.y, acc2 = a1.x, acc3 = a1.y;

    int j = row_ptr[node];
    const int end = row_ptr[node + 1];

    int s0, s1, s2, s3, s4, s5, s6, s7;
    bool have = (j + 8 <= end);
    if (have) {
        s0 = csr_src[j];     s1 = csr_src[j + 1];
        s2 = csr_src[j + 2]; s3 = csr_src[j + 3];
        s4 = csr_src[j + 4]; s5 = csr_src[j + 5];
        s6 = csr_src[j + 6]; s7 = csr_src[j + 7];
    }
    while (have) {
        const int jn = j + 8;
        const bool haven = (jn + 8 <= end);
        int t0, t1, t2, t3, t4, t5, t6, t7;
        if (haven) {           // prefetch next batch's indices (issues before gathers)
            t0 = csr_src[jn];     t1 = csr_src[jn + 1];
            t2 = csr_src[jn + 2]; t3 = csr_src[jn + 3];
            t4 = csr_src[jn + 4]; t5 = csr_src[jn + 5];
            t6 = csr_src[jn + 6]; t7 = csr_src[jn + 7];
        }
        uint2 u0 = h2[(size_t)s0 * 32 + l];
        uint2 u1 = h2[(size_t)s1 * 32 + l];
        uint2 u2 = h2[(size_t)s2 * 32 + l];
        uint2 u3 = h2[(size_t)s3 * 32 + l];
        uint2 u4 = h2[(size_t)s4 * 32 + l];
        uint2 u5 = h2[(size_t)s5 * 32 + l];
        uint2 u6 = h2[(size_t)s6 * 32 + l];
        uint2 u7 = h2[(size_t)s7 * 32 + l];
        float2 v0 = h2f(u0.x), w0 = h2f(u0.y), v1 = h2f(u1.x), w1 = h2f(u1.y);
        float2 v2 = h2f(u2.x), w2 = h2f(u2.y), v3 = h2f(u3.x), w3 = h2f(u3.y);
        float2 v4 = h2f(u4.x), w4 = h2f(u4.y), v5 = h2f(u5.x), w5 = h2f(u5.y);
        float2 v6 = h2f(u6.x), w6 = h2f(u6.y), v7 = h2f(u7.x), w7 = h2f(u7.y);
        acc0 += ((v0.x + v1.x) + (v2.x + v3.x)) + ((v4.x + v5.x) + (v6.x + v7.x));
        acc1 += ((v0.y + v1.y) + (v2.y + v3.y)) + ((v4.y + v5.y) + (v6.y + v7.y));
        acc2 += ((w0.x + w1.x) + (w2.x + w3.x)) + ((w4.x + w5.x) + (w6.x + w7.x));
        acc3 += ((w0.y + w1.y) + (w2.y + w3.y)) + ((w4.y + w5.y) + (w6.y + w7.y));
        s0 = t0; s1 = t1; s2 = t2; s3 = t3; s4 = t4; s5 = t5; s6 = t6; s7 = t7;
        j = jn;
        have = haven;
    }
    for (; j < end; ++j) {
        uint2 u = h2[(size_t)csr_src[j] * 32 + l];
        float2 v = h2f(u.x), w = h2f(u.y);
        acc0 += v.x; acc1 += v.y; acc2 += w.x; acc3 += w.y;
    }

    const float di = dinv[node];
    const float4 bv = reinterpret_cast<const float4*>(bias)[l];
    float o0 = fmaf(di, acc0, bv.x);
    float o1 = fmaf(di, acc1, bv.y);
    float o2 = fmaf(di, acc2, bv.z);
    float o3 = fmaf(di, acc3, bv.w);

    if constexpr (F16OUT) {
        o0 = fmaxf(o0, 0.f); o1 = fmaxf(o1, 0.f);
        o2 = fmaxf(o2, 0.f); o3 = fmaxf(o3, 0.f);
        const int swz = (((l >> 1) ^ (node & 7)) << 1) | (l & 1);
        f16x4 o = {(f16)o0, (f16)o1, (f16)o2, (f16)o3};
        *reinterpret_cast<f16x4*>((f16*)outv + (size_t)node * HID + swz * 4) = o;
    } else {
        *reinterpret_cast<float4*>((float*)outv + (size_t)node * HID + l * 4) =
            make_float4(o0, o1, o2, o3);
    }
}

// ================= launch =================

extern "C" void kernel_launch(void* const* d_in, const int* in_sizes, int n_in,
                              void* d_out, int out_size, void* d_ws, size_t ws_size,
                              hipStream_t stream) {
    const float* x  = (const float*)d_in[0];
    const int*   ei = (const int*)  d_in[1];
    const float* W0 = (const float*)d_in[2];
    const float* b0 = (const float*)d_in[3];
    const float* W1 = (const float*)d_in[4];
    const float* b1 = (const float*)d_in[5];
    const float* W2 = (const float*)d_in[6];
    const float* b2 = (const float*)d_in[7];

    const int N = in_sizes[0] / HID;
    const int E = in_sizes[1] / 2;
    const int* row = ei;        // sources
    const int* col = ei + E;    // destinations

    const int nb_n = (N + 255) / 256;

    // workspace layout
    f16*   h16     = (f16*)d_ws;                      // [N,128] f16 (= h', dinv-scaled)
    float* dinv    = (float*)(h16 + (size_t)N * HID); // [N]
    int*   cnt8    = (int*)(dinv + N);                // [8][N]
    int*   row_ptr = cnt8 + (size_t)8 * N;            // [N+1]
    int*   fill    = row_ptr + (N + 1);               // [N]
    int*   bsum    = fill + N;                        // [nb_n]
    int*   csr_src = bsum + nb_n;                     // [E]
    f16*   wt      = (f16*)(csr_src + E);             // [3*32768]
    f16*   wt0     = wt;
    f16*   wt1     = wt + 32768;
    f16*   wt2     = wt + 65536;
    f16*   act     = (f16*)d_out;                     // layers 0,1 activation (f16, swizzled, relu'd)
    float* out     = (float*)d_out;                   // final f32 output

    const int nb_gemm  = (N + BR - 1) / BR;
    const int nb_agg   = (N + 7) / 8;                 // 2 nodes per wave
    const int nb_chunk = (E + FILL_CHUNK - 1) / FILL_CHUNK;
    const int nb_fill  = nb_chunk * 4;                // 4 windows

    // ---- CSR build + W prep ----
    (void)hipMemsetAsync(cnt8, 0, (size_t)8 * N * sizeof(int), stream);
    k_prep_count<<<nb_chunk + 48, 256, 0, stream>>>(W0, W1, W2, wt, col, cnt8, E, N);
    k_scan_block<<<nb_n, 256, 0, stream>>>(cnt8, row_ptr, bsum, dinv, N);
    k_scan_bsum <<<1, 1024, 0, stream>>>(bsum, nb_n);
    k_scan_add  <<<nb_n, 256, 0, stream>>>(row_ptr, bsum, fill, N, E);
    k_fill      <<<nb_fill, 256, 0, stream>>>(row, col, fill, csr_src, E, N);

    // ---- layer 0: x (f32) -> h16 -> act (f16, swizzled+relu) ----
    k_gemm<0>      <<<nb_gemm, 512, 0, stream>>>(x, wt0, dinv, h16, N);
    k_agg_csr<true><<<nb_agg, 256, 0, stream>>>(h16, csr_src, row_ptr, dinv, b0, act, N);
    // ---- layer 1: act -> h16 -> act ----
    k_gemm<1>      <<<nb_gemm, 512, 0, stream>>>(act, wt1, dinv, h16, N);
    k_agg_csr<true><<<nb_agg, 256, 0, stream>>>(h16, csr_src, row_ptr, dinv, b1, act, N);
    // ---- layer 2: act -> h16 -> out (f32) ----
    k_gemm<1>      <<<nb_gemm, 512, 0, stream>>>(act, wt2, dinv, h16, N);
    k_agg_csr<false><<<nb_agg, 256, 0, stream>>>(h16, csr_src, row_ptr, dinv, b2, out, N);
}